// Round 2
// baseline (102.487 us; speedup 1.0000x reference)
//
#include <hip/hip_runtime.h>
#include <hip/hip_fp16.h>

#define NQ   13
#define DIM  8192
#define PI_F 3.14159265358979323846f
#define NT   512     // 8 waves/block; grid 512 -> 2 blocks/CU -> 4 waves/SIMD
#define NAMP 16      // amplitudes per thread (4-bit register window)

// Single LDS layout: slot L(i) = i + 4*(i>>5) (half2 slots, 1 slot = 1 bank dword).
// Verified: both patterns' 4x b128 accesses hit the 8-dword/bank floor (conflict-free).
#define NSLOT 9216   // L(8191) = 9211, rounded up

// Pattern A: i = (t<<4)|j.  reg bits {0,1,2,3}=qubits{12,11,10,9},
//            lane bits {4..9}=qubits{8..3} (t bits 0..5), wave bits {10,11,12}.
// Pattern B: i = (j&3) | ((t&31)<<2) | (((t>>5)&1)<<10) | (((t>>6)&7)<<7) | ((j>>2)<<11).
//            reg bits {0,1,11,12}: j bits 2,3 = qubits 1,0; lane bit 5 = i bit 10 = qubit 2.
__device__ __forceinline__ int baseA(int t) { return 16 * t + 4 * (t >> 1); }
__device__ __forceinline__ int baseB(int t, int g) {
  int m = t & 31;
  return 4 * m + 4 * (m >> 3) + 144 * ((t >> 6) & 7) + 1152 * ((t >> 5) & 1) + 2304 * g;
}

union F4H { float4 f; __half2 h[4]; };

__device__ __forceinline__ void rsincos(float x, float* s, float* c) {
  const float INV2PI = 0.15915494309189535f;
  const float TWOPI  = 6.283185307179586f;
  float r = x * INV2PI;
  r -= rintf(r);
  float ang = r * TWOPI;
  *s = __sinf(ang);
  *c = __cosf(ang);
}

// ---- fp32 helpers
__device__ __forceinline__ float2 f2fma(float s, float2 a, float2 b) {
  return make_float2(fmaf(s, a.x, b.x), fmaf(s, a.y, b.y));
}
__device__ __forceinline__ float2 f2add(float2 a, float2 b) {
  return make_float2(a.x + b.x, a.y + b.y);
}
__device__ __forceinline__ float2 f2sub(float2 a, float2 b) {
  return make_float2(a.x - b.x, a.y - b.y);
}
__device__ __forceinline__ float2 cphase(float2 v, float cs, float sn) {
  return make_float2(fmaf(cs, v.x, -sn * v.y), fmaf(cs, v.y, sn * v.x));
}
__device__ __forceinline__ float2 cmul(float2 a, float2 b) {
  return make_float2(fmaf(a.x, b.x, -a.y * b.y), fmaf(a.x, b.y, a.y * b.x));
}

// ---- cross-lane xor exchange: DPP (pure VALU) for masks 1,2; shfl otherwise
template<int MASK>
__device__ __forceinline__ int xorLaneI(int x) {
  if constexpr (MASK == 1)
    return __builtin_amdgcn_update_dpp(x, x, 0xB1, 0xF, 0xF, false);  // quad_perm [1,0,3,2]
  else if constexpr (MASK == 2)
    return __builtin_amdgcn_update_dpp(x, x, 0x4E, 0xF, 0xF, false);  // quad_perm [2,3,0,1]
  else
    return __shfl_xor(x, MASK, 64);
}
template<int MASK>
__device__ __forceinline__ __half2 xorLaneH(__half2 v) {
  union { __half2 h; int i; } u; u.h = v;
  u.i = xorLaneI<MASK>(u.i);
  return u.h;
}
template<int MASK>
__device__ __forceinline__ float xorLaneF(float v) {
  union { float f; int i; } u; u.f = v;
  u.i = xorLaneI<MASK>(u.i);
  return u.f;
}

// ---- LDS access (always packed fp16, 4x b128 per thread, both patterns)
__device__ __forceinline__ void loadAh(const __half2* __restrict__ sAmp, int t, __half2* amp) {
  const __half2* p = sAmp + baseA(t);
  #pragma unroll
  for (int k = 0; k < 4; k++) {
    F4H u; u.f = *reinterpret_cast<const float4*>(p + 4 * k);
    #pragma unroll
    for (int c = 0; c < 4; c++) amp[4 * k + c] = u.h[c];
  }
}
__device__ __forceinline__ void storeAh(__half2* __restrict__ sAmp, int t, const __half2* amp) {
  __half2* p = sAmp + baseA(t);
  #pragma unroll
  for (int k = 0; k < 4; k++) {
    F4H u;
    #pragma unroll
    for (int c = 0; c < 4; c++) u.h[c] = amp[4 * k + c];
    *reinterpret_cast<float4*>(p + 4 * k) = u.f;
  }
}
__device__ __forceinline__ void loadBh(const __half2* __restrict__ sAmp, int t, __half2* amp) {
  #pragma unroll
  for (int g = 0; g < 4; g++) {
    F4H u; u.f = *reinterpret_cast<const float4*>(sAmp + baseB(t, g));
    #pragma unroll
    for (int c = 0; c < 4; c++) amp[4 * g + c] = u.h[c];
  }
}
__device__ __forceinline__ void storeBh(__half2* __restrict__ sAmp, int t, const __half2* amp) {
  #pragma unroll
  for (int g = 0; g < 4; g++) {
    F4H u;
    #pragma unroll
    for (int c = 0; c < 4; c++) u.h[c] = amp[4 * g + c];
    *reinterpret_cast<float4*>(sAmp + baseB(t, g)) = u.f;
  }
}

// ---- fp32 register-bit gate math (shear rotation, exact)
template<int KB>
__device__ __forceinline__ void fwht_bit(float2* amp) {
  #pragma unroll
  for (int j = 0; j < NAMP; j++) if (!(j & (1 << KB))) {
    int j1 = j | (1 << KB);
    float2 a0 = amp[j], a1 = amp[j1];
    amp[j]  = f2add(a0, a1);
    amp[j1] = f2sub(a0, a1);
  }
}
template<int KB>
__device__ __forceinline__ void applyRy(float2* amp, float ta, float sa) {
  #pragma unroll
  for (int j = 0; j < NAMP; j++) if (!(j & (1 << KB))) {
    int j1 = j | (1 << KB);
    amp[j]  = f2fma(-ta, amp[j1], amp[j]);
    amp[j1] = f2fma( sa, amp[j],  amp[j1]);
    amp[j]  = f2fma(-ta, amp[j1], amp[j]);
  }
}

// ---- fp16 lane-bit gates: partner via xor exchange, direct rotation (2 ops/amp)
// Ry: bit0 lane: a' = c*a - s*p ; bit1 lane: a' = c*a + s*p
template<int MASK>
__device__ __forceinline__ void laneRyH(__half2* amp, __half2 c2, __half2 spm) {
  #pragma unroll
  for (int j = 0; j < NAMP; j++) {
    __half2 p = xorLaneH<MASK>(amp[j]);
    amp[j] = __hfma2(spm, p, __hmul2(c2, amp[j]));
  }
}
// FWHT: bit0 lane: a' = a + p ; bit1 lane: a' = p - a  ->  a' = sgn*a + p
template<int MASK>
__device__ __forceinline__ void laneFwhtH(__half2* amp, __half2 sgn) {
  #pragma unroll
  for (int j = 0; j < NAMP; j++) {
    __half2 p = xorLaneH<MASK>(amp[j]);
    amp[j] = __hfma2(sgn, amp[j], p);
  }
}
// fp32 FWHT lane stage (bits 4 and 10)
template<int MASK>
__device__ __forceinline__ void laneFwhtF(float2* amp, float sgn) {
  #pragma unroll
  for (int j = 0; j < NAMP; j++) {
    float px = xorLaneF<MASK>(amp[j].x);
    float py = xorLaneF<MASK>(amp[j].y);
    amp[j].x = fmaf(sgn, amp[j].x, px);
    amp[j].y = fmaf(sgn, amp[j].y, py);
  }
}

// phase tree over a 4-bit window.
// PAT 0 (A): base i-bits 4..12 = t bits 0..8; window {0,1,2,3}
// PAT 1 (B): base i-bits {2,3,4,5,6,10,7,8,9} = t bits 0..8; window {0,1,11,12}
template<int PAT>
__device__ __forceinline__ void buildTree(const float* __restrict__ w, float bias,
                                          int t, float* s) {
  float base = bias;
  if constexpr (PAT == 0) {
    #pragma unroll
    for (int k = 0; k < 9; k++) base += ((t >> k) & 1) ? w[4 + k] : 0.0f;
  } else {
    constexpr int BM[9] = {2, 3, 4, 5, 6, 10, 7, 8, 9};
    #pragma unroll
    for (int k = 0; k < 9; k++) base += ((t >> k) & 1) ? w[BM[k]] : 0.0f;
  }
  constexpr int PA[4] = {0, 1, 2, 3};
  constexpr int PB[4] = {0, 1, 11, 12};
  s[0] = base;
  #pragma unroll
  for (int k = 0; k < 4; k++) {
    float wp = w[(PAT == 0) ? PA[k] : PB[k]];
    #pragma unroll
    for (int m = 0; m < (1 << k); m++) s[m | (1 << k)] = s[m] + wp;
  }
}

// psi *= exp(i*phi(i)), phi = u + 0.5*(v^2 - A2); INIT writes unit phase
template<int PAT, bool INIT>
__device__ __forceinline__ void featureDiag(float2* amp,
                                            const float* __restrict__ wX,
                                            const float* __restrict__ wA,
                                            const float* __restrict__ cons, int t) {
  float u[NAMP], v[NAMP];
  buildTree<PAT>(wX, cons[0], t, u);
  buildTree<PAT>(wA, cons[1], t, v);
  float A2 = cons[2];
  #pragma unroll
  for (int j = 0; j < NAMP; j++) {
    float phi = u[j] + 0.5f * (v[j] * v[j] - A2);
    float sn, cs; rsincos(phi, &sn, &cs);
    if constexpr (INIT) amp[j] = make_float2(cs, sn);
    else                amp[j] = cphase(amp[j], cs, sn);
  }
}

// psi *= ENT(i)*exp(i*rho(i)) in pattern A (i=(t<<4)|j); rho = Rz layer phase.
// ENT split: t-pairs (runtime, once) ^ boundary (j bit3 & t bit0) ^ j-pairs (const).
__device__ __forceinline__ void applyDiagA(float2* amp,
                                           const float* __restrict__ wb,
                                           const float* __restrict__ eR,
                                           const float* __restrict__ eI,
                                           float bias, int t) {
  float base = bias;
  #pragma unroll
  for (int k = 0; k < 9; k++) base += ((t >> k) & 1) ? wb[4 + k] : 0.0f;
  float2 c[16];
  { float sn, cs; rsincos(base, &sn, &cs); c[0] = make_float2(cs, sn); }
  #pragma unroll
  for (int k = 0; k < 4; k++) {
    float2 e = make_float2(eR[k], eI[k]);
    #pragma unroll
    for (int m = 0; m < (1 << k); m++) c[m | (1 << k)] = cmul(c[m], e);
  }
  int st = __popc(t & (t >> 1)) & 1;           // pairs inside t (i bits >= 4)
  int tb = t & 1;                              // boundary partner (i bit 4)
  #pragma unroll
  for (int j = 0; j < 16; j++) {
    int sgb = st ^ (((j >> 3) & tb)) ^ (__popc(j & (j >> 1)) & 1);  // j-part folds
    float sgn = sgb ? -1.0f : 1.0f;
    amp[j] = cphase(amp[j], c[j].x * sgn, c[j].y * sgn);
  }
}

// (512,4): 8 waves/block, VGPR cap 128 so 2 blocks/CU = 4 waves/SIMD resident.
__global__ __launch_bounds__(NT, 4) void qc_kernel(
    const float* __restrict__ xin,
    const float* __restrict__ thin,
    const float* __restrict__ bin,
    float* __restrict__ out) {
  __shared__ alignas(16) __half2 sAmp[NSLOT];
  __shared__ float gTA[65], gSA[65];      // fp32 shear coeffs, indexed l*13+qubit
  __shared__ __half2 hC2[65], hS2[65];    // packed (c,c),(s,s) for fp16 lane gates
  __shared__ float gBbit[65];             // Rz b by [l*13 + bitpos], bitpos = 12-q
  __shared__ float eBr[65], eBi[65];      // cos(b), sin(b) by [l*13 + bitpos]
  __shared__ float wX[13], wA[13];        // -2x, -2a by bitpos
  __shared__ float cons[8];               // 0:X 1:A 2:A2 3..7:-0.5*sum b_l
  __shared__ float red[NT / 64];

  const int t = threadIdx.x;
  const int lane = t & 63;
  const int b = blockIdx.x;

  if (t < NQ) {
    float xq = xin[b * NQ + t];
    float aq = PI_F - xq;
    wX[12 - t] = -2.0f * xq;
    wA[12 - t] = -2.0f * aq;
  }
  if (t < 65) {
    float av = thin[2 * t];
    float bv = thin[2 * t + 1];
    float ca = cosf(0.5f * av);
    float sa = sinf(0.5f * av);
    float ta = sa / (1.0f + ca);
    gTA[t] = ta;
    gSA[t] = sa;
    hC2[t] = __float2half2_rn(ca);
    hS2[t] = __float2half2_rn(sa);
    int l = t / NQ, q = t % NQ;
    int s = l * NQ + (12 - q);
    gBbit[s] = bv;
    eBr[s] = cosf(bv);
    eBi[s] = sinf(bv);
  }
  __syncthreads();
  if (t == 0) {
    float X = 0.f, A = 0.f, A2 = 0.f;
    for (int p = 0; p < NQ; p++) {
      float xq = -0.5f * wX[p], aq = -0.5f * wA[p];
      X += xq; A += aq; A2 += aq * aq;
    }
    cons[0] = X; cons[1] = A; cons[2] = A2;
    for (int l = 0; l < 5; l++) {
      float s = 0.f;
      for (int p = 0; p < NQ; p++) s += gBbit[l * NQ + p];
      cons[3 + l] = -0.5f * s;
    }
  }
  __syncthreads();

  // ---- A0: init psi = exp(i*phi); FWHT bits 0..3 (reg fp32), 4 (DPP fp32),
  //          5..9 (lane fp16)
  {
    float2 amp[NAMP];
    featureDiag<0, true>(amp, wX, wA, cons, t);
    fwht_bit<0>(amp); fwht_bit<1>(amp); fwht_bit<2>(amp); fwht_bit<3>(amp);
    laneFwhtF<1>(amp, (lane & 1) ? -1.0f : 1.0f);
    __half2 h[NAMP];
    #pragma unroll
    for (int j = 0; j < NAMP; j++) h[j] = __float22half2_rn(amp[j]);
    const __half2 P1 = __float2half2_rn(1.0f), M1 = __float2half2_rn(-1.0f);
    laneFwhtH<2>(h,  (lane & 2)  ? M1 : P1);
    laneFwhtH<4>(h,  (lane & 4)  ? M1 : P1);
    laneFwhtH<8>(h,  (lane & 8)  ? M1 : P1);
    laneFwhtH<16>(h, (lane & 16) ? M1 : P1);
    laneFwhtH<32>(h, (lane & 32) ? M1 : P1);
    storeAh(sAmp, t, h);
  }
  __syncthreads();

  // ---- B0: FWHT bits 10 (lane fp32), 11,12 (reg fp32); 2nd feature diag;
  //          Ry_0 on q1,q0 (reg fp32) and q2 (lane fp16)
  {
    __half2 h[NAMP];
    loadBh(sAmp, t, h);
    float2 amp[NAMP];
    #pragma unroll
    for (int j = 0; j < NAMP; j++) amp[j] = __half22float2(h[j]);
    laneFwhtF<32>(amp, (lane & 32) ? -1.0f : 1.0f);   // i bit 10
    fwht_bit<2>(amp); fwht_bit<3>(amp);               // i bits 11,12
    featureDiag<1, false>(amp, wX, wA, cons, t);
    applyRy<2>(amp, gTA[1], gSA[1]);                  // qubit 1
    applyRy<3>(amp, gTA[0], gSA[0]);                  // qubit 0
    #pragma unroll
    for (int j = 0; j < NAMP; j++) h[j] = __float22half2_rn(amp[j]);
    __half2 s2 = hS2[2];
    __half2 spm = (lane & 32) ? s2 : __hneg2(s2);
    laneRyH<32>(h, hC2[2], spm);                      // qubit 2
    storeBh(sAmp, t, h);
  }
  __syncthreads();

  // ---- Layers: A_l (q8..q3 lane fp16; q12..q9 reg fp32; diag_l / readout)
  //              B_{l+1} (q2 lane fp16; q1,q0 reg fp32)
  float acc = 0.0f;
  for (int l = 0; l < 5; l++) {
    const int g = l * NQ;
    {
      __half2 h[NAMP];
      loadAh(sAmp, t, h);
      // lane gates, masks 1,2 via DPP (VALU), 4..32 via shfl
      {
        __half2 s2, spm;
        s2 = hS2[g + 8]; spm = (lane & 1)  ? s2 : __hneg2(s2); laneRyH<1>(h,  hC2[g + 8], spm);
        s2 = hS2[g + 7]; spm = (lane & 2)  ? s2 : __hneg2(s2); laneRyH<2>(h,  hC2[g + 7], spm);
        s2 = hS2[g + 6]; spm = (lane & 4)  ? s2 : __hneg2(s2); laneRyH<4>(h,  hC2[g + 6], spm);
        s2 = hS2[g + 5]; spm = (lane & 8)  ? s2 : __hneg2(s2); laneRyH<8>(h,  hC2[g + 5], spm);
        s2 = hS2[g + 4]; spm = (lane & 16) ? s2 : __hneg2(s2); laneRyH<16>(h, hC2[g + 4], spm);
        s2 = hS2[g + 3]; spm = (lane & 32) ? s2 : __hneg2(s2); laneRyH<32>(h, hC2[g + 3], spm);
      }
      float2 amp[NAMP];
      #pragma unroll
      for (int j = 0; j < NAMP; j++) amp[j] = __half22float2(h[j]);
      applyRy<0>(amp, gTA[g + 12], gSA[g + 12]);
      applyRy<1>(amp, gTA[g + 11], gSA[g + 11]);
      applyRy<2>(amp, gTA[g + 10], gSA[g + 10]);
      applyRy<3>(amp, gTA[g + 9],  gSA[g + 9]);
      if (l < 4) {
        applyDiagA(amp, gBbit + g, eBr + g, eBi + g, cons[3 + l], t);
        #pragma unroll
        for (int j = 0; j < NAMP; j++) h[j] = __float22half2_rn(amp[j]);
        storeAh(sAmp, t, h);
      } else {
        // all L4 non-diagonal gates applied; trailing Rz invisible in |amp|^2
        int pt = __popc(t) & 1;
        #pragma unroll
        for (int j = 0; j < NAMP; j++) {
          float p2 = fmaf(amp[j].x, amp[j].x, amp[j].y * amp[j].y);
          acc += ((pt + __popc(j)) & 1) ? -p2 : p2;
        }
      }
    }
    if (l < 4) {
      __syncthreads();
      const int g1 = g + NQ;
      {
        __half2 h[NAMP];
        loadBh(sAmp, t, h);
        __half2 s2 = hS2[g1 + 2];
        __half2 spm = (lane & 32) ? s2 : __hneg2(s2);
        laneRyH<32>(h, hC2[g1 + 2], spm);             // qubit 2
        float2 amp[NAMP];
        #pragma unroll
        for (int j = 0; j < NAMP; j++) amp[j] = __half22float2(h[j]);
        applyRy<2>(amp, gTA[g1 + 1], gSA[g1 + 1]);    // qubit 1
        applyRy<3>(amp, gTA[g1 + 0], gSA[g1 + 0]);    // qubit 0
        #pragma unroll
        for (int j = 0; j < NAMP; j++) h[j] = __float22half2_rn(amp[j]);
        storeBh(sAmp, t, h);
      }
      __syncthreads();
    }
  }

  // block reduction (raw scale 2^26)
  #pragma unroll
  for (int off = 32; off > 0; off >>= 1) acc += __shfl_down(acc, off, 64);
  if ((t & 63) == 0) red[t >> 6] = acc;
  __syncthreads();
  if (t == 0) {
    float total = 0.f;
    #pragma unroll
    for (int w = 0; w < NT / 64; w++) total += red[w];
    float logit = total * (1.0f / 67108864.0f) + bin[0];
    out[b * 2 + 0] = -logit;
    out[b * 2 + 1] = logit;
  }
}

extern "C" void kernel_launch(void* const* d_in, const int* in_sizes, int n_in,
                              void* d_out, int out_size, void* d_ws, size_t ws_size,
                              hipStream_t stream) {
  const float* x  = (const float*)d_in[0];
  const float* th = (const float*)d_in[1];
  const float* bi = (const float*)d_in[2];
  float* out = (float*)d_out;
  int B = in_sizes[0] / NQ;   // 512
  qc_kernel<<<B, NT, 0, stream>>>(x, th, bi, out);
}